// Round 1
// baseline (619.756 us; speedup 1.0000x reference)
//
#include <hip/hip_runtime.h>
#include <hip/hip_bf16.h>
#include <math.h>

#define NN 50000
#define ROWS 64
#define NHID 256

typedef __bf16 bf16_t;
typedef __bf16 bf16x8 __attribute__((ext_vector_type(8)));
typedef float f32x4 __attribute__((ext_vector_type(4)));

static __device__ inline f32x4 mfma16(bf16x8 a, bf16x8 b, f32x4 c) {
  return __builtin_amdgcn_mfma_f32_16x16x32_bf16(a, b, c, 0, 0, 0);
}

static __device__ inline float sigm(float z) { return 1.f / (1.f + __expf(-z)); }
static __device__ inline float tanh_fast(float z) {
  z = fminf(fmaxf(z, -15.f), 15.f);
  float e = __expf(2.f * z);
  return (e - 1.f) / (e + 1.f);
}

// ---------------- prep: weights fp32 -> bf16, transposed to B-operand layout ----------------
// wtg layout: [gate][n=0..255][k=0..511]  (k<256: W_g[k][n], k>=256: Th_g[k-256][n])
// wtl layout: [n=0..255][k=0..255]        (W_lin[k][n])
// biasg: [gate][n] = bth_g[n] + b_g[n]
__global__ void prep_kernel(const float* __restrict__ Wi, const float* __restrict__ Wf,
                            const float* __restrict__ Wc, const float* __restrict__ Wo,
                            const float* __restrict__ Ti, const float* __restrict__ Tf,
                            const float* __restrict__ Tc, const float* __restrict__ To,
                            const float* __restrict__ Wl,
                            const float* __restrict__ bthi, const float* __restrict__ bthf,
                            const float* __restrict__ bthc, const float* __restrict__ btho,
                            const float* __restrict__ bi, const float* __restrict__ bfv,
                            const float* __restrict__ bc, const float* __restrict__ bo,
                            bf16_t* __restrict__ wtg, bf16_t* __restrict__ wtl,
                            float* __restrict__ biasg) {
  int id = blockIdx.x * 256 + threadIdx.x;
  if (id < 65536) {
    int g = id >> 14, j = id & 16383;
    int k0 = (j >> 8) * 8, n = j & 255;
    const float* W = (g == 0) ? Wi : (g == 1) ? Wf : (g == 2) ? Wc : Wo;
    const float* T = (g == 0) ? Ti : (g == 1) ? Tf : (g == 2) ? Tc : To;
    bf16x8 o;
#pragma unroll
    for (int t = 0; t < 8; ++t) {
      int k = k0 + t;
      float v = (k < 256) ? W[k * 256 + n] : T[(k - 256) * 256 + n];
      o[t] = (bf16_t)v;
    }
    *reinterpret_cast<bf16x8*>(&wtg[(g * 256 + n) * 512 + k0]) = o;
  } else if (id < 65536 + 8192) {
    int j = id - 65536;
    int k0 = (j >> 8) * 8, n = j & 255;
    bf16x8 o;
#pragma unroll
    for (int t = 0; t < 8; ++t) o[t] = (bf16_t)Wl[(k0 + t) * 256 + n];
    *reinterpret_cast<bf16x8*>(&wtl[n * 256 + k0]) = o;
  } else if (id < 65536 + 8192 + 1024) {
    int j = id - 65536 - 8192;
    int g = j >> 8, n = j & 255;
    const float* bt = (g == 0) ? bthi : (g == 1) ? bthf : (g == 2) ? bthc : btho;
    const float* bb = (g == 0) ? bi : (g == 1) ? bfv : (g == 2) ? bc : bo;
    biasg[g * 256 + n] = bt[n] + bb[n];
  }
}

// ---------------- main fused kernel ----------------
// One block = 64 rows. 4 waves; wave w owns output columns [w*64, w*64+64).
// Stages X=[x|h] bf16 into 64KB LDS (XOR-swizzled), runs 4 gate GEMMs (K=512)
// sequentially with fused LSTM math, then relu(H) @ W_lin through LDS.
__global__ __launch_bounds__(256, 2)
void gclstm_kernel(const float* __restrict__ x, const float* __restrict__ hin,
                   const float* __restrict__ cin,
                   const bf16_t* __restrict__ wtg, const bf16_t* __restrict__ wtl,
                   const float* __restrict__ biasg,
                   const float* __restrict__ wci, const float* __restrict__ wcf,
                   const float* __restrict__ wco, const float* __restrict__ blin,
                   float* __restrict__ dout) {
  __shared__ __align__(16) char smem[65536];

  const int tid = threadIdx.x;
  const int lane = tid & 63;
  const int w = tid >> 6;
  const int r0 = blockIdx.x * ROWS;

  // ---- stage X = [x|h] as bf16 into LDS, XOR swizzle byte ^= (row&7)<<4 ----
#pragma unroll
  for (int it = 0; it < 16; ++it) {
    int p = it * 256 + tid;
    int row = p >> 6;
    int ce = (p & 63) * 8;  // element column 0..504 in the 512-wide X row
    int grow = r0 + row;
    grow = (grow < NN) ? grow : (NN - 1);
    const float* src = (ce < 256) ? (x + grow * 256 + ce) : (hin + grow * 256 + (ce - 256));
    float4 v0 = *reinterpret_cast<const float4*>(src);
    float4 v1 = *reinterpret_cast<const float4*>(src + 4);
    bf16x8 o;
    o[0] = (bf16_t)v0.x; o[1] = (bf16_t)v0.y; o[2] = (bf16_t)v0.z; o[3] = (bf16_t)v0.w;
    o[4] = (bf16_t)v1.x; o[5] = (bf16_t)v1.y; o[6] = (bf16_t)v1.z; o[7] = (bf16_t)v1.w;
    int byte = row * 1024 + ((ce * 2) ^ ((row & 7) << 4));
    *reinterpret_cast<bf16x8*>(smem + byte) = o;
  }
  __syncthreads();

  const int rl = lane & 15;          // A-row / B-col / D-col within 16-tile
  const int ko = (lane >> 4) * 8;    // k offset within 32-chunk
  const int wc0 = w * 64;            // this wave's first output column
  const int rowoff = (lane >> 4) * 4;  // D-row offset within 16-tile

  f32x4 acc[4][4];
  f32x4 st[4][4];

#define XADDR(ROW, COLE) \
  reinterpret_cast<const bf16x8*>(smem + (ROW) * 1024 + ((((COLE) * 2)) ^ (((ROW) & 7) << 4)))

#define GATE_MM(G)                                                                        \
  {                                                                                       \
    const bf16_t* wb = wtg + ((G) * 256 + wc0 + rl) * 512 + ko;                           \
    _Pragma("unroll") for (int rt = 0; rt < 4; ++rt)                                      \
        _Pragma("unroll") for (int ct = 0; ct < 4; ++ct)                                  \
            acc[rt][ct] = f32x4{0.f, 0.f, 0.f, 0.f};                                      \
    _Pragma("unroll") for (int ks = 0; ks < 16; ++ks) {                                   \
      bf16x8 afr[4], bfr[4];                                                              \
      _Pragma("unroll") for (int rt = 0; rt < 4; ++rt)                                    \
          afr[rt] = *XADDR(rt * 16 + rl, ks * 32 + ko);                                   \
      _Pragma("unroll") for (int ct = 0; ct < 4; ++ct)                                    \
          bfr[ct] = *reinterpret_cast<const bf16x8*>(wb + ct * 16 * 512 + ks * 32);       \
      _Pragma("unroll") for (int rt = 0; rt < 4; ++rt)                                    \
          _Pragma("unroll") for (int ct = 0; ct < 4; ++ct)                                \
              acc[rt][ct] = mfma16(afr[rt], bfr[ct], acc[rt][ct]);                        \
    }                                                                                     \
  }

  // ---------- gate i ----------
  GATE_MM(0);
#pragma unroll
  for (int ct = 0; ct < 4; ++ct) {
    int col = wc0 + ct * 16 + rl;
    float wciv = wci[col];
    float bv = biasg[0 * 256 + col];
#pragma unroll
    for (int rt = 0; rt < 4; ++rt) {
      int rbase = r0 + rt * 16 + rowoff;
#pragma unroll
      for (int j = 0; j < 4; ++j) {
        int r = rbase + j;
        int rc = (r < NN) ? r : (NN - 1);
        float cv = cin[rc * NHID + col];
        st[rt][ct][j] = sigm(acc[rt][ct][j] + wciv * cv + bv);  // st = I
      }
    }
  }

  // ---------- gate c (candidate) ----------
  GATE_MM(2);
#pragma unroll
  for (int ct = 0; ct < 4; ++ct) {
    int col = wc0 + ct * 16 + rl;
    float bv = biasg[2 * 256 + col];
#pragma unroll
    for (int rt = 0; rt < 4; ++rt) {
#pragma unroll
      for (int j = 0; j < 4; ++j) {
        st[rt][ct][j] *= tanh_fast(acc[rt][ct][j] + bv);  // st = I*T
      }
    }
  }

  // ---------- gate f ----------
  GATE_MM(1);
#pragma unroll
  for (int ct = 0; ct < 4; ++ct) {
    int col = wc0 + ct * 16 + rl;
    float wcfv = wcf[col];
    float bv = biasg[1 * 256 + col];
#pragma unroll
    for (int rt = 0; rt < 4; ++rt) {
      int rbase = r0 + rt * 16 + rowoff;
#pragma unroll
      for (int j = 0; j < 4; ++j) {
        int r = rbase + j;
        int rc = (r < NN) ? r : (NN - 1);
        float cv = cin[rc * NHID + col];
        float fg = sigm(acc[rt][ct][j] + wcfv * cv + bv);
        float C = fg * cv + st[rt][ct][j];
        if (r < NN) dout[2 * NN * NHID + r * NHID + col] = C;  // c0 output
        st[rt][ct][j] = C;
      }
    }
  }

  // ---------- gate o ----------
  GATE_MM(3);
#pragma unroll
  for (int ct = 0; ct < 4; ++ct) {
    int col = wc0 + ct * 16 + rl;
    float wcov = wco[col];
    float bv = biasg[3 * 256 + col];
#pragma unroll
    for (int rt = 0; rt < 4; ++rt) {
      int rbase = r0 + rt * 16 + rowoff;
#pragma unroll
      for (int j = 0; j < 4; ++j) {
        int r = rbase + j;
        float C = st[rt][ct][j];
        float O = sigm(acc[rt][ct][j] + wcov * C + bv);
        float H = O * tanh_fast(C);
        if (r < NN) dout[NN * NHID + r * NHID + col] = H;  // h0 output
        st[rt][ct][j] = H;
      }
    }
  }

  // ---------- exchange relu(H) through LDS (aliases X buffer) ----------
  __syncthreads();  // all waves done reading X tile
  bf16_t* ht = reinterpret_cast<bf16_t*>(smem);  // [64][264]
#pragma unroll
  for (int ct = 0; ct < 4; ++ct) {
#pragma unroll
    for (int rt = 0; rt < 4; ++rt) {
#pragma unroll
      for (int j = 0; j < 4; ++j) {
        ht[(rt * 16 + rowoff + j) * 264 + wc0 + ct * 16 + rl] =
            (bf16_t)fmaxf(st[rt][ct][j], 0.f);
      }
    }
  }
  __syncthreads();

  // ---------- out = relu(H) @ W_lin + b_lin ----------
#pragma unroll
  for (int rt = 0; rt < 4; ++rt)
#pragma unroll
    for (int ct = 0; ct < 4; ++ct) acc[rt][ct] = f32x4{0.f, 0.f, 0.f, 0.f};
  {
    const bf16_t* wlb = wtl + (wc0 + rl) * 256 + ko;
#pragma unroll
    for (int ks = 0; ks < 8; ++ks) {
      bf16x8 afr[4], bfr[4];
#pragma unroll
      for (int rt = 0; rt < 4; ++rt)
        afr[rt] = *reinterpret_cast<const bf16x8*>(&ht[(rt * 16 + rl) * 264 + ks * 32 + ko]);
#pragma unroll
      for (int ct = 0; ct < 4; ++ct)
        bfr[ct] = *reinterpret_cast<const bf16x8*>(wlb + ct * 16 * 256 + ks * 32);
#pragma unroll
      for (int rt = 0; rt < 4; ++rt)
#pragma unroll
        for (int ct = 0; ct < 4; ++ct)
          acc[rt][ct] = mfma16(afr[rt], bfr[ct], acc[rt][ct]);
    }
  }
#pragma unroll
  for (int ct = 0; ct < 4; ++ct) {
    int col = wc0 + ct * 16 + rl;
    float bl = blin[col];
#pragma unroll
    for (int rt = 0; rt < 4; ++rt) {
      int rbase = r0 + rt * 16 + rowoff;
#pragma unroll
      for (int j = 0; j < 4; ++j) {
        int r = rbase + j;
        if (r < NN) dout[r * NHID + col] = acc[rt][ct][j] + bl;  // out
      }
    }
  }
#undef GATE_MM
#undef XADDR
}

extern "C" void kernel_launch(void* const* d_in, const int* in_sizes, int n_in,
                              void* d_out, int out_size, void* d_ws, size_t ws_size,
                              hipStream_t stream) {
  const float* x = (const float*)d_in[0];
  // d_in[1] edge_index, d_in[2] edge_weight: mathematically unused (K=1 ChebConv)
  const float* h = (const float*)d_in[3];
  const float* c = (const float*)d_in[4];
  const float* Wi = (const float*)d_in[5];
  const float* Wf = (const float*)d_in[6];
  const float* Wc = (const float*)d_in[7];
  const float* Wo = (const float*)d_in[8];
  const float* Ti = (const float*)d_in[9];
  const float* Tf = (const float*)d_in[10];
  const float* Tc = (const float*)d_in[11];
  const float* To = (const float*)d_in[12];
  const float* bthi = (const float*)d_in[13];
  const float* bthf = (const float*)d_in[14];
  const float* bthc = (const float*)d_in[15];
  const float* btho = (const float*)d_in[16];
  const float* wci = (const float*)d_in[17];
  const float* wcf = (const float*)d_in[18];
  const float* wco = (const float*)d_in[19];
  const float* bi = (const float*)d_in[20];
  const float* bfv = (const float*)d_in[21];
  const float* bc = (const float*)d_in[22];
  const float* bo = (const float*)d_in[23];
  const float* Wl = (const float*)d_in[24];
  const float* blin = (const float*)d_in[25];

  char* ws = (char*)d_ws;
  bf16_t* wtg = (bf16_t*)ws;                          // 4*256*512*2 = 1,048,576 B
  bf16_t* wtl = (bf16_t*)(ws + 4 * 256 * 512 * 2);    // 256*256*2 = 131,072 B
  float* biasg = (float*)(ws + 4 * 256 * 512 * 2 + 256 * 256 * 2);  // 4*256*4 B

  prep_kernel<<<292, 256, 0, stream>>>(Wi, Wf, Wc, Wo, Ti, Tf, Tc, To, Wl,
                                       bthi, bthf, bthc, btho, bi, bfv, bc, bo,
                                       wtg, wtl, biasg);

  int grid = (NN + ROWS - 1) / ROWS;  // 782
  gclstm_kernel<<<grid, 256, 0, stream>>>(x, h, c, wtg, wtl, biasg,
                                          wci, wcf, wco, blin, (float*)d_out);
}